// Round 1
// baseline (3634.463 us; speedup 1.0000x reference)
//
#include <hip/hip_runtime.h>
#include <hip/hip_bf16.h>
#include <type_traits>

// Problem constants
#define NN_  42
#define E_   41
#define H_   128
#define NIN_ 32
#define FF_  256
#define OUT_ 128
#define L_   2
#define NH_  4
#define HD_  32
#define FB_  4096   // B*A

// Workspace layout (float offsets). Total 955136 floats = 3.82 MB.
#define WT_IN   0        // [32][128]   Wt_in[k][h] = W_in[h][k]
#define QKVH_WT 4096     // [L][NH][128][96] per-head (q|k|v) cols, transposed
#define QKVH_B  102400   // [L][NH][96]
#define AO_WT   103168   // [L][128][128] ao_wt[k][j] = attn_out_w[j][k]
#define FF1_WT  135936   // [L][128][256]
#define FF2_WT  201472   // [L][256][128]
#define WOUT_T  267008   // [5376][128]  WoT[k][j] = W_out[j][k]
#define WS_FLOATS 955136

// ---------------- weight pre-transpose ----------------
__global__ void prep_weights(const float* __restrict__ W_in,
                             const float* __restrict__ qkv_w,
                             const float* __restrict__ qkv_b,
                             const float* __restrict__ ao_w,
                             const float* __restrict__ ff1_w,
                             const float* __restrict__ ff2_w,
                             const float* __restrict__ W_out,
                             float* __restrict__ ws) {
  int t = blockIdx.x * 256 + threadIdx.x;
  if (t < 4096) { int k = t >> 7, h = t & 127; ws[WT_IN + t] = W_in[h * 32 + k]; return; }
  int u = t - 4096;
  if (u < 98304) {  // qkv per-head transposed
    int lh = u / 12288, r = u % 12288;
    int l = lh >> 2, h = lh & 3;
    int k = r / 96, j = r % 96;
    int part = j >> 5, d = j & 31;
    ws[QKVH_WT + u] = qkv_w[(l * 384 + part * 128 + h * 32 + d) * 128 + k];
    return;
  }
  u -= 98304;
  if (u < 768) {
    int lh = u / 96, j = u % 96;
    int l = lh >> 2, h = lh & 3;
    int part = j >> 5, d = j & 31;
    ws[QKVH_B + u] = qkv_b[l * 384 + part * 128 + h * 32 + d];
    return;
  }
  u -= 768;
  if (u < 32768) {
    int l = u >> 14, r = u & 16383;
    int k = r >> 7, j = r & 127;
    ws[AO_WT + u] = ao_w[(l * 128 + j) * 128 + k];
    return;
  }
  u -= 32768;
  if (u < 65536) {
    int l = u >> 15, r = u & 32767;
    int k = r >> 8, j = r & 255;
    ws[FF1_WT + u] = ff1_w[(l * 256 + j) * 128 + k];
    return;
  }
  u -= 65536;
  if (u < 65536) {
    int l = u >> 15, r = u & 32767;
    int k = r >> 7, j = r & 127;
    ws[FF2_WT + u] = ff2_w[(l * 128 + j) * 256 + k];
    return;
  }
  u -= 65536;
  if (u < 688128) {
    int k = u >> 7, j = u & 127;
    ws[WOUT_T + u] = W_out[j * 5376 + k];
  }
}

// ---------------- tiled [42 x NC] = [42 x K] @ [K x NC] GEMM on LDS A ----------------
// MODE: 0 = store(+bias), 1 = relu store(+bias), 2 = add-to-dst(+bias), 3 = add-to-dst (no bias)
template <int TX, int C, int K, int MODE, typename ST, typename DT>
__device__ __forceinline__ void gemm_tile(const float* __restrict__ Wt, int ldW, int colbase,
                                          const float* __restrict__ bias,
                                          const ST* __restrict__ xsrc, int ldx,
                                          DT* __restrict__ dst, int ldd, int tid) {
  constexpr int TY = 256 / TX;
  constexpr int R = (NN_ + TY - 1) / TY;
  const int tx = tid % TX, ty = tid / TX;
  int rowi[R];
#pragma unroll
  for (int r = 0; r < R; ++r) { int i = ty + TY * r; rowi[r] = (i < NN_) ? i : (NN_ - 1); }
  float acc[R][C];
#pragma unroll
  for (int r = 0; r < R; ++r)
#pragma unroll
    for (int c = 0; c < C; ++c) acc[r][c] = 0.f;
  const float* Wp = Wt + colbase + tx;
#pragma unroll 4
  for (int k = 0; k < K; ++k) {
    float w[C];
#pragma unroll
    for (int c = 0; c < C; ++c) w[c] = Wp[k * ldW + TX * c];
#pragma unroll
    for (int r = 0; r < R; ++r) {
      float xv = (float)xsrc[rowi[r] * ldx + k];
#pragma unroll
      for (int c = 0; c < C; ++c) acc[r][c] = fmaf(xv, w[c], acc[r][c]);
    }
  }
#pragma unroll
  for (int r = 0; r < R; ++r) {
    int i = ty + TY * r;
    if (i < NN_) {
#pragma unroll
      for (int c = 0; c < C; ++c) {
        int j = tx + TX * c;
        float v = acc[r][c];
        if constexpr (MODE != 3) v += bias[j];
        if constexpr (MODE == 1) v = fmaxf(v, 0.f);
        if constexpr (MODE == 2 || MODE == 3) {
          dst[i * ldd + j] += v;  // DT == float for these modes
        } else {
          if constexpr (std::is_same_v<DT, __hip_bfloat16>) dst[i * ldd + j] = __float2bfloat16(v);
          else dst[i * ldd + j] = v;
        }
      }
    }
  }
}

// In-place LayerNorm over rows of x[42][128]; one wave per row slice.
__device__ __forceinline__ void ln_rows(float* x, const float* __restrict__ g,
                                        const float* __restrict__ b, int tid) {
  const int w = tid >> 6, lane = tid & 63;
  const float g0 = g[lane], g1 = g[64 + lane], b0 = b[lane], b1 = b[64 + lane];
  for (int r = 0; r < 11; ++r) {
    int i = w + 4 * r;
    if (i >= NN_) break;  // wave-uniform
    float v0 = x[i * 128 + lane];
    float v1 = x[i * 128 + 64 + lane];
    float s = v0 + v1, ss = v0 * v0 + v1 * v1;
#pragma unroll
    for (int m = 1; m < 64; m <<= 1) { s += __shfl_xor(s, m, 64); ss += __shfl_xor(ss, m, 64); }
    float mu = s * 0.0078125f;
    float var = fmaxf(ss * 0.0078125f - mu * mu, 0.f);
    float rs = rsqrtf(var + 1e-5f);
    x[i * 128 + lane] = (v0 - mu) * rs * g0 + b0;
    x[i * 128 + 64 + lane] = (v1 - mu) * rs * g1 + b1;
  }
}

// ---------------- fused per-tree transformer ----------------
__global__ __launch_bounds__(256, 2) void tree_fused(
    const float* __restrict__ forest, const int* __restrict__ adjacency,
    const int* __restrict__ node_order, const float* __restrict__ b_in,
    const float* __restrict__ ao_b, const float* __restrict__ ff1_b,
    const float* __restrict__ ff2_b, const float* __restrict__ ln1_g,
    const float* __restrict__ ln1_b, const float* __restrict__ ln2_g,
    const float* __restrict__ ln2_b, const float* __restrict__ b_out,
    const float* __restrict__ lnf_g, const float* __restrict__ lnf_b,
    const float* __restrict__ ws, float* __restrict__ out) {
  const int f = blockIdx.x;
  const int tid = threadIdx.x;

  __shared__ float xs[NN_ * 128];            // 21504 B  persistent x
  __shared__ float buf1[NN_ * 128];          // 21504 B  per-head qkv (ld 99) / forest stage / ff h chunk1 (as bf16)
  __shared__ __hip_bfloat16 obf[NN_ * 128];  // 10752 B  attn o concat / ff h chunk0
  __shared__ float sc[NN_ * 43];             // 7224 B   scores / output scratch
  __shared__ int adj_s[E_ * 3];
  __shared__ int depth_s[NN_];
  // total ~61.6 KB

  // ---- stage 0: init ----
  for (int i = tid; i < NN_ * 128; i += 256) xs[i] = 0.f;
  for (int i = tid; i < NN_ * NIN_; i += 256) buf1[i] = forest[f * (NN_ * NIN_) + i];
  if (tid < E_ * 3) adj_s[tid] = adjacency[f * (E_ * 3) + tid];
  if (tid >= 128 && tid < 192) {  // wave 2 computes depths
    int lane = tid - 128;
    int v = (lane < NN_) ? node_order[f * NN_ + lane] : 0;
    int mx = v;
#pragma unroll
    for (int m = 1; m < 64; m <<= 1) mx = max(mx, __shfl_xor(mx, m, 64));
    if (lane < NN_) depth_s[lane] = mx - v;
  }
  __syncthreads();

  // ---- stage 1: positional encoding into xs (wave 0; parent idx < child idx) ----
  if (tid < 64) {
    for (int e = 0; e < E_; ++e) {
      int p = adj_s[e * 3], c = adj_s[e * 3 + 1], s = adj_s[e * 3 + 2];
      if (p >= 0 && c >= 0) {
        int pl = p - f * NN_, cl = c - f * NN_;
        int si = s + 1; si = si < 0 ? 0 : (si > 2 ? 2 : si);
        int idx = depth_s[pl] * 3 + si;
        float a0 = (tid == idx) ? 1.f : 0.f;
        float a1 = (tid + 64 == idx) ? 1.f : 0.f;
        xs[cl * 128 + tid] = xs[pl * 128 + tid] + a0;
        xs[cl * 128 + 64 + tid] = xs[pl * 128 + 64 + tid] + a1;
      }
    }
  }
  __syncthreads();

  // ---- stage 2: embed  xs += forest @ W_in^T + b_in ----
  gemm_tile<64, 2, NIN_, 2, float, float>(ws + WT_IN, 128, 0, b_in, buf1, NIN_, xs, 128, tid);
  __syncthreads();

  // ---- encoder layers ----
  for (int l = 0; l < L_; ++l) {
    // attention, one head at a time
    for (int h = 0; h < NH_; ++h) {
      // q|k|v for this head -> buf1 with row stride 99 (gcd(99,32)=1: conflict-free column walks)
      gemm_tile<32, 3, 128, 0, float, float>(ws + QKVH_WT + (l * 4 + h) * 12288, 96, 0,
                                             ws + QKVH_B + (l * 4 + h) * 96, xs, 128, buf1, 99, tid);
      __syncthreads();
      // scores
      for (int idx = tid; idx < NN_ * NN_; idx += 256) {
        int i = idx / NN_, j = idx - i * NN_;
        float s = 0.f;
#pragma unroll
        for (int d = 0; d < HD_; ++d) s = fmaf(buf1[i * 99 + d], buf1[j * 99 + 32 + d], s);
        sc[i * 43 + j] = s * 0.17677669529663687f;  // 1/sqrt(32)
      }
      __syncthreads();
      // softmax (42 rows, one thread each)
      if (tid < NN_) {
        float mx = -1e30f;
        for (int j = 0; j < NN_; ++j) mx = fmaxf(mx, sc[tid * 43 + j]);
        float sum = 0.f;
        for (int j = 0; j < NN_; ++j) { float e = expf(sc[tid * 43 + j] - mx); sc[tid * 43 + j] = e; sum += e; }
        float inv = 1.f / sum;
        for (int j = 0; j < NN_; ++j) sc[tid * 43 + j] *= inv;
      }
      __syncthreads();
      // P @ V -> obf (bf16) columns h*32..h*32+31
      for (int idx = tid; idx < NN_ * HD_; idx += 256) {
        int i = idx >> 5, d = idx & 31;
        float o = 0.f;
#pragma unroll
        for (int j = 0; j < NN_; ++j) o = fmaf(sc[i * 43 + j], buf1[j * 99 + 64 + d], o);
        obf[i * 128 + h * 32 + d] = __float2bfloat16(o);
      }
      __syncthreads();
    }
    // xs += o @ attn_out_w^T + ao_b   (residual fused)
    gemm_tile<64, 2, 128, 2, __hip_bfloat16, float>(ws + AO_WT + l * 16384, 128, 0,
                                                    ao_b + l * 128, obf, 128, xs, 128, tid);
    __syncthreads();
    ln_rows(xs, ln1_g + l * 128, ln1_b + l * 128, tid);
    __syncthreads();
    // FF: h = relu(xs@W1^T+b1) in two 128-col chunks (bf16 staging), then xs += h@W2^T+b2
    gemm_tile<64, 2, 128, 1, float, __hip_bfloat16>(ws + FF1_WT + l * 32768, 256, 0,
                                                    ff1_b + l * 256, xs, 128, obf, 128, tid);
    __syncthreads();
    gemm_tile<64, 2, 128, 1, float, __hip_bfloat16>(ws + FF1_WT + l * 32768, 256, 128,
                                                    ff1_b + l * 256 + 128, xs, 128,
                                                    (__hip_bfloat16*)buf1, 128, tid);
    __syncthreads();
    gemm_tile<64, 2, 128, 2, __hip_bfloat16, float>(ws + FF2_WT + l * 32768, 128, 0,
                                                    ff2_b + l * 128, obf, 128, xs, 128, tid);
    __syncthreads();
    gemm_tile<64, 2, 128, 3, __hip_bfloat16, float>(ws + FF2_WT + l * 32768 + 128 * 128, 128, 0,
                                                    nullptr, (const __hip_bfloat16*)buf1, 128,
                                                    xs, 128, tid);
    __syncthreads();
    ln_rows(xs, ln2_g + l * 128, ln2_b + l * 128, tid);
    __syncthreads();
  }

  // ---- output projection: y[j] = x.flat(5376) . WoT[:,j] + b_out, then LayerNorm ----
  {
    int j = tid & 127, half = tid >> 7;
    const float* WoT = ws + WOUT_T;
    float acc = 0.f;
    for (int ii = 0; ii < 21; ++ii) {
      int i = half * 21 + ii;
      const float* xrow = xs + i * 128;
      const float* wcol = WoT + (i * 128) * 128 + j;
#pragma unroll 4
      for (int k = 0; k < 128; ++k) acc = fmaf(xrow[k], wcol[k * 128], acc);
    }
    sc[half * 128 + j] = acc;
  }
  __syncthreads();
  if (tid < 128) sc[256 + tid] = sc[tid] + sc[128 + tid] + b_out[tid];
  __syncthreads();
  if (tid < 64) {
    float a0 = sc[256 + tid], a1 = sc[320 + tid];
    float s = a0 + a1, ss = a0 * a0 + a1 * a1;
#pragma unroll
    for (int m = 1; m < 64; m <<= 1) { s += __shfl_xor(s, m, 64); ss += __shfl_xor(ss, m, 64); }
    if (tid == 0) {
      float mu = s * 0.0078125f;
      float var = fmaxf(ss * 0.0078125f - mu * mu, 0.f);
      sc[384] = mu;
      sc[385] = rsqrtf(var + 1e-5f);
    }
  }
  __syncthreads();
  if (tid < 128) {
    float mu = sc[384], rs = sc[385];
    out[(size_t)f * OUT_ + tid] = (sc[256 + tid] - mu) * rs * lnf_g[tid] + lnf_b[tid];
  }
}

extern "C" void kernel_launch(void* const* d_in, const int* in_sizes, int n_in,
                              void* d_out, int out_size, void* d_ws, size_t ws_size,
                              hipStream_t stream) {
  const float* forest     = (const float*)d_in[0];
  const int*   adjacency  = (const int*)d_in[1];
  const int*   node_order = (const int*)d_in[2];
  const float* W_in       = (const float*)d_in[3];
  const float* b_in       = (const float*)d_in[4];
  const float* qkv_w      = (const float*)d_in[5];
  const float* qkv_b      = (const float*)d_in[6];
  const float* ao_w       = (const float*)d_in[7];
  const float* ao_b       = (const float*)d_in[8];
  const float* ff1_w      = (const float*)d_in[9];
  const float* ff1_b      = (const float*)d_in[10];
  const float* ff2_w      = (const float*)d_in[11];
  const float* ff2_b      = (const float*)d_in[12];
  const float* ln1_g      = (const float*)d_in[13];
  const float* ln1_b      = (const float*)d_in[14];
  const float* ln2_g      = (const float*)d_in[15];
  const float* ln2_b      = (const float*)d_in[16];
  const float* W_out      = (const float*)d_in[17];
  const float* b_out      = (const float*)d_in[18];
  const float* lnf_g      = (const float*)d_in[19];
  const float* lnf_b      = (const float*)d_in[20];
  float* ws  = (float*)d_ws;
  float* out = (float*)d_out;

  prep_weights<<<dim3((WS_FLOATS + 255) / 256), dim3(256), 0, stream>>>(
      W_in, qkv_w, qkv_b, ao_w, ff1_w, ff2_w, W_out, ws);
  tree_fused<<<dim3(FB_), dim3(256), 0, stream>>>(
      forest, adjacency, node_order, b_in, ao_b, ff1_b, ff2_b,
      ln1_g, ln1_b, ln2_g, ln2_b, b_out, lnf_g, lnf_b, ws, out);
}

// Round 2
// 846.629 us; speedup vs baseline: 4.2929x; 4.2929x over previous
//
#include <hip/hip_runtime.h>
#include <hip/hip_bf16.h>

typedef __bf16 bf16x8 __attribute__((ext_vector_type(8)));
typedef __bf16 bf16x4 __attribute__((ext_vector_type(4)));
typedef float  f32x4  __attribute__((ext_vector_type(4)));

#define MFMA(a,b,c) __builtin_amdgcn_mfma_f32_16x16x32_bf16((a),(b),(c),0,0,0)

// problem constants
#define NN_  42
#define E_   41
#define FB_  4096
#define SCALE_ 0.17677669529663687f  // 1/sqrt(32)

// ws layout, element offsets into __bf16* ws
#define WB_WIN  0         // [128][32]
#define WB_QKV  4096      // [L][384][128]
#define WB_AO   102400    // [L][128][128]
#define WB_FF1  135168    // [L][256][128]
#define WB_FF2  200704    // [L][128][256]
#define WB_WOUT 266240    // [128][5376]
#define WB_X    954368    // [4096][5376] staged x_final (bf16)
#define PREP_N  954368

// ---------------- weight cast to bf16 (layouts preserved == MFMA B-operand layout) ----
__global__ void prep_bf16(const float* __restrict__ W_in, const float* __restrict__ qkv_w,
                          const float* __restrict__ ao_w, const float* __restrict__ ff1_w,
                          const float* __restrict__ ff2_w, const float* __restrict__ W_out,
                          __bf16* __restrict__ wb) {
  int i = blockIdx.x * 256 + threadIdx.x;
  float v;
  if      (i < 4096)   v = W_in[i];
  else if (i < 102400) v = qkv_w[i - 4096];
  else if (i < 135168) v = ao_w[i - 102400];
  else if (i < 200704) v = ff1_w[i - 135168];
  else if (i < 266240) v = ff2_w[i - 200704];
  else if (i < 954368) v = W_out[i - 266240];
  else return;
  wb[i] = (__bf16)v;
}

__device__ __forceinline__ bf16x8 ld8(const __bf16* p) { return *(const bf16x8*)p; }

// C = A[48xK] * B^T tiles for NB column-tiles; A in LDS (lda halfwords), B rows contiguous-k.
template <int NB, int KS>
__device__ __forceinline__ void gemm3xN(const __bf16* A, int lda, const __bf16* const (&B)[NB],
                                        int c16, int quad, f32x4 (&acc)[NB][3]) {
#pragma unroll
  for (int i = 0; i < NB; ++i) {
    acc[i][0] = f32x4{0,0,0,0}; acc[i][1] = f32x4{0,0,0,0}; acc[i][2] = f32x4{0,0,0,0};
  }
#pragma unroll
  for (int ks = 0; ks < KS; ++ks) {
    int ko = ks * 32 + quad * 8;
    bf16x8 a0 = ld8(A + c16 * lda + ko);
    bf16x8 a1 = ld8(A + (16 + c16) * lda + ko);
    bf16x8 a2 = ld8(A + (32 + c16) * lda + ko);
#pragma unroll
    for (int i = 0; i < NB; ++i) {
      bf16x8 b = ld8(B[i] + ko);
      acc[i][0] = MFMA(a0, b, acc[i][0]);
      acc[i][1] = MFMA(a1, b, acc[i][1]);
      acc[i][2] = MFMA(a2, b, acc[i][2]);
    }
  }
}

// qkv epilogue for one N-tile t (0..5): part=t>>1 (q/k/v), sub=t&1
__device__ __forceinline__ void qkv_store(int t, int h, f32x4 (&a)[3], const float* qkv_b_l,
                                          __bf16* qh, __bf16* kh, __bf16* vt, int c16, int quad) {
  int part = t >> 1, sub = t & 1;
  float bias = qkv_b_l[part * 128 + h * 32 + sub * 16 + c16];
#pragma unroll
  for (int mt = 0; mt < 3; ++mt) {
    if (part == 2) {
      bf16x4 pk;
#pragma unroll
      for (int r = 0; r < 4; ++r) {
        int row = mt * 16 + quad * 4 + r;
        float v = a[mt][r] + bias;
        pk[r] = (__bf16)(row < NN_ ? v : 0.f);
      }
      *(bf16x4*)(vt + (sub * 16 + c16) * 72 + mt * 16 + quad * 4) = pk;
    } else {
      __bf16* dst = (part == 0) ? qh : kh;
#pragma unroll
      for (int r = 0; r < 4; ++r) {
        int row = mt * 16 + quad * 4 + r;
        float v = a[mt][r] + bias;
        float vv = (row < NN_) ? (part == 0 ? v * SCALE_ : v) : 0.f;
        dst[row * 40 + sub * 16 + c16] = (__bf16)vv;
      }
    }
  }
}

__device__ __forceinline__ f32x4 score_tile(int mt, int nt, const __bf16* qh, const __bf16* kh,
                                            int c16, int quad) {
  int ko = quad * 8;
  bf16x8 a = ld8(qh + (mt * 16 + c16) * 40 + ko);
  bf16x8 b = ld8(kh + (nt * 16 + c16) * 40 + ko);
  f32x4 z{0,0,0,0};
  return MFMA(a, b, z);
}

__device__ __forceinline__ void smax_part(f32x4 s, int mt, int nt, int c16, int quad, float* pmax) {
  bool valid = (nt * 16 + c16) < NN_;
#pragma unroll
  for (int r = 0; r < 4; ++r) {
    float mv = valid ? s[r] : -3.0e38f;
    mv = fmaxf(mv, __shfl_xor(mv, 1)); mv = fmaxf(mv, __shfl_xor(mv, 2));
    mv = fmaxf(mv, __shfl_xor(mv, 4)); mv = fmaxf(mv, __shfl_xor(mv, 8));
    if (c16 == 0) pmax[(mt * 16 + quad * 4 + r) * 3 + nt] = mv;
  }
}

__device__ __forceinline__ void sexp_part(f32x4 s, int mt, int nt, int c16, int quad,
                                          const float* statsA, float* psum, __bf16* P) {
  int j = nt * 16 + c16; bool valid = j < NN_;
#pragma unroll
  for (int r = 0; r < 4; ++r) {
    int row = mt * 16 + quad * 4 + r;
    float m = statsA[row];
    float e = valid ? __expf(s[r] - m) : 0.f;
    P[row * 72 + j] = (__bf16)e;
    float es = e;
    es += __shfl_xor(es, 1); es += __shfl_xor(es, 2);
    es += __shfl_xor(es, 4); es += __shfl_xor(es, 8);
    if (c16 == 0) psum[row * 3 + nt] = es;
  }
}

__device__ __forceinline__ void pv_tile(int mt, int nt, int h, const __bf16* P, const __bf16* vt,
                                        const float* statsB, __bf16* obf, int c16, int quad) {
  f32x4 acc{0,0,0,0};
#pragma unroll
  for (int ks = 0; ks < 2; ++ks) {
    int ko = ks * 32 + quad * 8;
    bf16x8 a = ld8(P + (mt * 16 + c16) * 72 + ko);
    bf16x8 b = ld8(vt + (nt * 16 + c16) * 72 + ko);
    acc = MFMA(a, b, acc);
  }
#pragma unroll
  for (int r = 0; r < 4; ++r) {
    int row = mt * 16 + quad * 4 + r;
    float v = acc[r] * statsB[row];
    obf[row * 136 + h * 32 + nt * 16 + c16] = (__bf16)(row < NN_ ? v : 0.f);
  }
}

// LN over rows; res in C-layout (cols (2w+nt)*16+c16); rewrites res + x_bf; 3 barriers.
__device__ __forceinline__ void ln_update(float (&res)[3][2][4], const float* __restrict__ g,
                                          const float* __restrict__ bb, __bf16* xbf, float* part,
                                          float* statsA, float* statsB, int tid, int w, int c16,
                                          int quad) {
#pragma unroll
  for (int mt = 0; mt < 3; ++mt)
#pragma unroll
    for (int r = 0; r < 4; ++r) {
      float s = res[mt][0][r] + res[mt][1][r];
      float ss = res[mt][0][r] * res[mt][0][r] + res[mt][1][r] * res[mt][1][r];
      s += __shfl_xor(s, 1); ss += __shfl_xor(ss, 1);
      s += __shfl_xor(s, 2); ss += __shfl_xor(ss, 2);
      s += __shfl_xor(s, 4); ss += __shfl_xor(ss, 4);
      s += __shfl_xor(s, 8); ss += __shfl_xor(ss, 8);
      if (c16 == 0) {
        int row = mt * 16 + quad * 4 + r;
        part[(w * 48 + row) * 2] = s; part[(w * 48 + row) * 2 + 1] = ss;
      }
    }
  __syncthreads();
  if (tid < 48) {
    float S = 0.f, SS = 0.f;
#pragma unroll
    for (int w2 = 0; w2 < 4; ++w2) { S += part[(w2 * 48 + tid) * 2]; SS += part[(w2 * 48 + tid) * 2 + 1]; }
    float mu = S * 0.0078125f;
    float var = fmaxf(SS * 0.0078125f - mu * mu, 0.f);
    statsA[tid] = mu; statsB[tid] = rsqrtf(var + 1e-5f);
  }
  __syncthreads();
  float gg[2], bv[2];
#pragma unroll
  for (int nt = 0; nt < 2; ++nt) { int col = (2 * w + nt) * 16 + c16; gg[nt] = g[col]; bv[nt] = bb[col]; }
#pragma unroll
  for (int mt = 0; mt < 3; ++mt)
#pragma unroll
    for (int r = 0; r < 4; ++r) {
      int row = mt * 16 + quad * 4 + r;
      float mu = statsA[row], rs = statsB[row];
#pragma unroll
      for (int nt = 0; nt < 2; ++nt) {
        float v = (res[mt][nt][r] - mu) * rs * gg[nt] + bv[nt];
        res[mt][nt][r] = v;
        xbf[row * 136 + (2 * w + nt) * 16 + c16] = (__bf16)(row < NN_ ? v : 0.f);
      }
    }
  __syncthreads();
}

// ---------------- per-tree fused encoder (MFMA) ----------------
__global__ __launch_bounds__(256, 3) void tree_enc(
    const float* __restrict__ forest, const int* __restrict__ adjacency,
    const int* __restrict__ node_order, const float* __restrict__ b_in,
    const float* __restrict__ qkv_b, const float* __restrict__ ao_b,
    const float* __restrict__ ff1_b, const float* __restrict__ ff2_b,
    const float* __restrict__ ln1_g, const float* __restrict__ ln1_b,
    const float* __restrict__ ln2_g, const float* __restrict__ ln2_b,
    const __bf16* __restrict__ wb, __bf16* __restrict__ Xg) {
  const int f = blockIdx.x, tid = threadIdx.x;
  const int lane = tid & 63, w = tid >> 6, c16 = lane & 15, quad = lane >> 4;

  __shared__ __bf16 xbf[48 * 136];                 // 13,056 B  persistent x (bf16 A-operand)
  __shared__ __bf16 vt[32 * 72];                   //  4,608 B  V^T for current head
  __shared__ alignas(16) unsigned char uni[28416]; // union: pos+fbf | obf+qh+kh+P | hbf
  __shared__ float pmax[144], psum[144], statsA[48], statsB[48], part[384];
  __shared__ int adj_s[E_ * 3];
  __shared__ int depth_s[48];

  float* pos = (float*)uni;                        // [48][128] f32
  __bf16* fbf = (__bf16*)(uni + 24576);            // [48][40]
  __bf16* obf = (__bf16*)uni;                      // [48][136]
  __bf16* qh  = (__bf16*)(uni + 13056);            // [48][40]
  __bf16* kh  = (__bf16*)(uni + 16896);            // [48][40]
  __bf16* P   = (__bf16*)(uni + 20736);            // [48][72]
  __bf16* hbf = (__bf16*)uni;                      // [48][264]

  // ---- stage 0: zero pos/fbf/vt, load adj, depths ----
  for (int i = tid; i < 6144; i += 256) pos[i] = 0.f;
  for (int i = tid; i < 960; i += 256) ((int*)fbf)[i] = 0;
  for (int i = tid; i < 1152; i += 256) ((int*)vt)[i] = 0;
  if (tid < E_ * 3) adj_s[tid] = adjacency[f * (E_ * 3) + tid];
  if (w == 1) {
    int v = (lane < NN_) ? node_order[f * NN_ + lane] : 0;
    int mx = v;
#pragma unroll
    for (int m = 1; m < 64; m <<= 1) mx = max(mx, __shfl_xor(mx, m));
    if (lane < 48) depth_s[lane] = (lane < NN_) ? (mx - v) : 0;
  }
  __syncthreads();

  // ---- stage 1: stage forest (bf16) + positional-encoding walk (wave 0) ----
  for (int i = tid; i < NN_ * 32; i += 256) {
    int r = i >> 5, c = i & 31;
    fbf[r * 40 + c] = (__bf16)forest[f * (NN_ * 32) + i];
  }
  if (w == 0) {
    for (int e = 0; e < E_; ++e) {
      int p = adj_s[e * 3], c = adj_s[e * 3 + 1], s = adj_s[e * 3 + 2];
      if (p >= 0 && c >= 0) {
        int pl = p - f * NN_, cl = c - f * NN_;
        int si = s + 1; si = si < 0 ? 0 : (si > 2 ? 2 : si);
        int idx = depth_s[pl] * 3 + si;
        float a0 = (lane == idx) ? 1.f : 0.f;
        float a1 = (lane + 64 == idx) ? 1.f : 0.f;
        pos[cl * 128 + lane] = pos[pl * 128 + lane] + a0;
        pos[cl * 128 + 64 + lane] = pos[pl * 128 + 64 + lane] + a1;
      }
    }
  }
  __syncthreads();

  // ---- stage 2: embed  x0 = forest @ W_in^T + b_in + pos ----
  float res[3][2][4];
  {
    const __bf16* Bw[2] = { wb + WB_WIN + ((2 * w) * 16 + c16) * 32,
                            wb + WB_WIN + ((2 * w + 1) * 16 + c16) * 32 };
    f32x4 ea[2][3];
    gemm3xN<2, 1>(fbf, 40, Bw, c16, quad, ea);
    float bi[2];
#pragma unroll
    for (int nt = 0; nt < 2; ++nt) bi[nt] = b_in[(2 * w + nt) * 16 + c16];
#pragma unroll
    for (int mt = 0; mt < 3; ++mt)
#pragma unroll
      for (int r = 0; r < 4; ++r) {
        int row = mt * 16 + quad * 4 + r;
#pragma unroll
        for (int nt = 0; nt < 2; ++nt) {
          int col = (2 * w + nt) * 16 + c16;
          float v = ea[nt][mt][r] + bi[nt] + pos[row * 128 + col];
          res[mt][nt][r] = v;
          xbf[row * 136 + col] = (__bf16)(row < NN_ ? v : 0.f);
        }
      }
  }
  __syncthreads();

  // ---- encoder layers ----
  for (int l = 0; l < 2; ++l) {
    const __bf16* qkvW = wb + WB_QKV + l * 384 * 128;
    const float* qkv_b_l = qkv_b + l * 384;

    for (int h = 0; h < 4; ++h) {
      // qkv for head h: N-tiles t: wave w -> {w} and {w+4 if w<2}
      {
        int t0 = w;
        const __bf16* B0 = qkvW + ((t0 >> 1) * 128 + h * 32 + (t0 & 1) * 16 + c16) * 128;
        if (w < 2) {
          int t1 = w + 4;
          const __bf16* Bs[2] = { B0, qkvW + ((t1 >> 1) * 128 + h * 32 + (t1 & 1) * 16 + c16) * 128 };
          f32x4 qa[2][3];
          gemm3xN<2, 4>(xbf, 136, Bs, c16, quad, qa);
          qkv_store(t0, h, qa[0], qkv_b_l, qh, kh, vt, c16, quad);
          qkv_store(t1, h, qa[1], qkv_b_l, qh, kh, vt, c16, quad);
        } else {
          const __bf16* Bs[1] = { B0 };
          f32x4 qa[1][3];
          gemm3xN<1, 4>(xbf, 136, Bs, c16, quad, qa);
          qkv_store(t0, h, qa[0], qkv_b_l, qh, kh, vt, c16, quad);
        }
      }
      __syncthreads();

      // scores: tiles tt = w, w+4 (always), 8 (w==0 only)
      int mt0 = w / 3, nt0 = w % 3;
      int mt1 = (w + 4) / 3, nt1 = (w + 4) % 3;
      f32x4 s0 = score_tile(mt0, nt0, qh, kh, c16, quad);
      f32x4 s1 = score_tile(mt1, nt1, qh, kh, c16, quad);
      f32x4 s2;
      if (w == 0) s2 = score_tile(2, 2, qh, kh, c16, quad);
      // zero P cols 48..63 (stale-NaN guard for PV K-step 1)
      for (int i = tid; i < 384; i += 256) { int row = i >> 3, d = i & 7; ((int*)P)[row * 36 + 24 + d] = 0; }
      smax_part(s0, mt0, nt0, c16, quad, pmax);
      smax_part(s1, mt1, nt1, c16, quad, pmax);
      if (w == 0) smax_part(s2, 2, 2, c16, quad, pmax);
      __syncthreads();
      if (tid < 48) statsA[tid] = fmaxf(fmaxf(pmax[tid * 3], pmax[tid * 3 + 1]), pmax[tid * 3 + 2]);
      __syncthreads();
      sexp_part(s0, mt0, nt0, c16, quad, statsA, psum, P);
      sexp_part(s1, mt1, nt1, c16, quad, statsA, psum, P);
      if (w == 0) sexp_part(s2, 2, 2, c16, quad, statsA, psum, P);
      __syncthreads();
      if (tid < 48) statsB[tid] = 1.f / (psum[tid * 3] + psum[tid * 3 + 1] + psum[tid * 3 + 2]);
      __syncthreads();
      // PV: tiles tt = w (always), w+4 (w<2)
      pv_tile(w >> 1, w & 1, h, P, vt, statsB, obf, c16, quad);
      if (w < 2) pv_tile(2, w & 1, h, P, vt, statsB, obf, c16, quad);
      __syncthreads();
    }

    // attn-out + residual
    {
      const __bf16* aoW = wb + WB_AO + l * 128 * 128;
      const __bf16* Bs[2] = { aoW + ((2 * w) * 16 + c16) * 128, aoW + ((2 * w + 1) * 16 + c16) * 128 };
      f32x4 aa[2][3];
      gemm3xN<2, 4>(obf, 136, Bs, c16, quad, aa);
      float ab[2];
#pragma unroll
      for (int nt = 0; nt < 2; ++nt) ab[nt] = ao_b[l * 128 + (2 * w + nt) * 16 + c16];
#pragma unroll
      for (int mt = 0; mt < 3; ++mt)
#pragma unroll
        for (int nt = 0; nt < 2; ++nt)
#pragma unroll
          for (int r = 0; r < 4; ++r) res[mt][nt][r] += aa[nt][mt][r] + ab[nt];
    }
    ln_update(res, ln1_g + l * 128, ln1_b + l * 128, xbf, part, statsA, statsB, tid, w, c16, quad);

    // FF1 -> hbf (relu, bf16)
    {
      const __bf16* f1W = wb + WB_FF1 + l * 256 * 128;
      const __bf16* Bs[4] = { f1W + ((4 * w) * 16 + c16) * 128, f1W + ((4 * w + 1) * 16 + c16) * 128,
                              f1W + ((4 * w + 2) * 16 + c16) * 128, f1W + ((4 * w + 3) * 16 + c16) * 128 };
      f32x4 fa[4][3];
      gemm3xN<4, 4>(xbf, 136, Bs, c16, quad, fa);
#pragma unroll
      for (int nt = 0; nt < 4; ++nt) {
        int col = (4 * w + nt) * 16 + c16;
        float b1 = ff1_b[l * 256 + col];
#pragma unroll
        for (int mt = 0; mt < 3; ++mt)
#pragma unroll
          for (int r = 0; r < 4; ++r) {
            int row = mt * 16 + quad * 4 + r;
            float v = fmaxf(fa[nt][mt][r] + b1, 0.f);
            hbf[row * 264 + col] = (__bf16)(row < NN_ ? v : 0.f);
          }
      }
    }
    __syncthreads();

    // FF2 + residual
    {
      const __bf16* f2W = wb + WB_FF2 + l * 128 * 256;
      const __bf16* Bs[2] = { f2W + ((2 * w) * 16 + c16) * 256, f2W + ((2 * w + 1) * 16 + c16) * 256 };
      f32x4 fa[2][3];
      gemm3xN<2, 8>(hbf, 264, Bs, c16, quad, fa);
      float fb2[2];
#pragma unroll
      for (int nt = 0; nt < 2; ++nt) fb2[nt] = ff2_b[l * 128 + (2 * w + nt) * 16 + c16];
#pragma unroll
      for (int mt = 0; mt < 3; ++mt)
#pragma unroll
        for (int nt = 0; nt < 2; ++nt)
#pragma unroll
          for (int r = 0; r < 4; ++r) res[mt][nt][r] += fa[nt][mt][r] + fb2[nt];
    }
    ln_update(res, ln2_g + l * 128, ln2_b + l * 128, xbf, part, statsA, statsB, tid, w, c16, quad);
  }

  // ---- stage out: copy x_final (bf16) to ws X[f][5376] ----
  {
    __bf16* Xf = Xg + (size_t)f * 5376;
    for (int c = tid; c < 672; c += 256) {
      int row = c >> 4, co = (c & 15) * 8;
      bf16x8 v = ld8(xbf + row * 136 + co);
      *(bf16x8*)(Xf + row * 128 + co) = v;
    }
  }
}

// ---------------- output projection + final LN: [4096 x 5376] @ [5376 x 128] ----------------
__global__ __launch_bounds__(256) void wout_k(const __bf16* __restrict__ X,
                                              const __bf16* __restrict__ Wb,
                                              const float* __restrict__ b_out,
                                              const float* __restrict__ lnf_g,
                                              const float* __restrict__ lnf_b,
                                              float* __restrict__ out) {
  const int blk = blockIdx.x, tid = threadIdx.x;
  const int lane = tid & 63, w = tid >> 6, c16 = lane & 15, quad = lane >> 4;
  __shared__ float cout[16 * 132];
  f32x4 acc0{0,0,0,0}, acc1{0,0,0,0};
  const __bf16* Ar = X + (size_t)(blk * 16 + c16) * 5376;
  const __bf16* B0 = Wb + (size_t)((2 * w) * 16 + c16) * 5376;
  const __bf16* B1 = Wb + (size_t)((2 * w + 1) * 16 + c16) * 5376;
#pragma unroll 4
  for (int ks = 0; ks < 168; ++ks) {
    int ko = ks * 32 + quad * 8;
    bf16x8 a = ld8(Ar + ko);
    acc0 = MFMA(a, ld8(B0 + ko), acc0);
    acc1 = MFMA(a, ld8(B1 + ko), acc1);
  }
#pragma unroll
  for (int nt = 0; nt < 2; ++nt) {
    int col = (2 * w + nt) * 16 + c16;
    float bias = b_out[col];
    f32x4 a = nt ? acc1 : acc0;
#pragma unroll
    for (int r = 0; r < 4; ++r) cout[(quad * 4 + r) * 132 + col] = a[r] + bias;
  }
  __syncthreads();
#pragma unroll
  for (int rr = 0; rr < 4; ++rr) {
    int row = w * 4 + rr;
    float v0 = cout[row * 132 + lane], v1 = cout[row * 132 + 64 + lane];
    float s = v0 + v1, ss = v0 * v0 + v1 * v1;
#pragma unroll
    for (int m = 1; m < 64; m <<= 1) { s += __shfl_xor(s, m); ss += __shfl_xor(ss, m); }
    float mu = s * 0.0078125f;
    float var = fmaxf(ss * 0.0078125f - mu * mu, 0.f);
    float rs = rsqrtf(var + 1e-5f);
    size_t o = (size_t)(blk * 16 + row) * 128;
    out[o + lane] = (v0 - mu) * rs * lnf_g[lane] + lnf_b[lane];
    out[o + 64 + lane] = (v1 - mu) * rs * lnf_g[64 + lane] + lnf_b[64 + lane];
  }
}

extern "C" void kernel_launch(void* const* d_in, const int* in_sizes, int n_in,
                              void* d_out, int out_size, void* d_ws, size_t ws_size,
                              hipStream_t stream) {
  const float* forest     = (const float*)d_in[0];
  const int*   adjacency  = (const int*)d_in[1];
  const int*   node_order = (const int*)d_in[2];
  const float* W_in       = (const float*)d_in[3];
  const float* b_in       = (const float*)d_in[4];
  const float* qkv_w      = (const float*)d_in[5];
  const float* qkv_b      = (const float*)d_in[6];
  const float* ao_w       = (const float*)d_in[7];
  const float* ao_b       = (const float*)d_in[8];
  const float* ff1_w      = (const float*)d_in[9];
  const float* ff1_b      = (const float*)d_in[10];
  const float* ff2_w      = (const float*)d_in[11];
  const float* ff2_b      = (const float*)d_in[12];
  const float* ln1_g      = (const float*)d_in[13];
  const float* ln1_b      = (const float*)d_in[14];
  const float* ln2_g      = (const float*)d_in[15];
  const float* ln2_b      = (const float*)d_in[16];
  const float* b_out      = (const float*)d_in[18];
  const float* lnf_g      = (const float*)d_in[19];
  const float* lnf_b      = (const float*)d_in[20];
  __bf16* wb = (__bf16*)d_ws;
  float* out = (float*)d_out;

  prep_bf16<<<dim3(PREP_N / 256), dim3(256), 0, stream>>>(W_in, qkv_w, ao_w, ff1_w, ff2_w,
                                                          (const float*)d_in[17], wb);
  tree_enc<<<dim3(FB_), dim3(256), 0, stream>>>(forest, adjacency, node_order, b_in, qkv_b, ao_b,
                                                ff1_b, ff2_b, ln1_g, ln1_b, ln2_g, ln2_b, wb,
                                                wb + WB_X);
  wout_k<<<dim3(FB_ / 16), dim3(256), 0, stream>>>(wb + WB_X, wb + WB_WOUT, b_out, lnf_g, lnf_b,
                                                   out);
}

// Round 3
// 602.273 us; speedup vs baseline: 6.0346x; 1.4057x over previous
//
#include <hip/hip_runtime.h>
#include <hip/hip_bf16.h>

typedef __bf16 bf16x8 __attribute__((ext_vector_type(8)));
typedef __bf16 bf16x4 __attribute__((ext_vector_type(4)));
typedef float  f32x4  __attribute__((ext_vector_type(4)));

#define MFMA(a,b,c) __builtin_amdgcn_mfma_f32_16x16x32_bf16((a),(b),(c),0,0,0)

// problem constants
#define NN_  42
#define E_   41
#define FB_  4096
#define SCALE_ 0.17677669529663687f  // 1/sqrt(32)

// ws layout, element offsets into __bf16* ws (layouts preserved == MFMA B-operand layout)
#define WB_WIN  0         // [128][32]
#define WB_QKV  4096      // [L][384][128]
#define WB_AO   102400    // [L][128][128]
#define WB_FF1  135168    // [L][256][128]
#define WB_FF2  200704    // [L][128][256]
#define WB_WOUT 266240    // [128][5376]
#define WB_X    954368    // [4096][5376] staged x_final (bf16)
#define PREP_N  954368

// smem byte offsets (all 16B-aligned)
#define SM_QK    0        // per-wave 6912 B: qk[48][72] (q:0..31,k:32..63) | fbf[48][40] | hbf[48][264]
#define SM_XO    27648    // xbf/obf [48][136] bf16 (aliased; one barrier guards swap)
#define SM_VT    40704    // per-wave 3584 B: vt[32][56] | pos bf16 [48][128]
#define SM_PART  55040    // float[384]
#define SM_SA    56576    // float[48]
#define SM_SB    56768    // float[48]
#define SM_ADJ   56960    // int[123]
#define SM_DEP   57456    // int[48]
#define SM_SZ    57648

// ---------------- weight cast to bf16 ----------------
__global__ void prep_bf16(const float* __restrict__ W_in, const float* __restrict__ qkv_w,
                          const float* __restrict__ ao_w, const float* __restrict__ ff1_w,
                          const float* __restrict__ ff2_w, const float* __restrict__ W_out,
                          __bf16* __restrict__ wb) {
  int i = blockIdx.x * 256 + threadIdx.x;
  float v;
  if      (i < 4096)   v = W_in[i];
  else if (i < 102400) v = qkv_w[i - 4096];
  else if (i < 135168) v = ao_w[i - 102400];
  else if (i < 200704) v = ff1_w[i - 135168];
  else if (i < 266240) v = ff2_w[i - 200704];
  else if (i < 954368) v = W_out[i - 266240];
  else return;
  wb[i] = (__bf16)v;
}

__device__ __forceinline__ bf16x8 ld8(const __bf16* p) { return *(const bf16x8*)p; }

__device__ __forceinline__ int pack2(float a, float b) {
  union { __bf16 h[2]; int i; } u;
  u.h[0] = (__bf16)a; u.h[1] = (__bf16)b;
  return u.i;
}

// C = A[48xK] * B^T for NB column-tiles; A in LDS (lda halfwords), B rows contiguous-k (global).
template <int NB, int KS>
__device__ __forceinline__ void gemm3xN(const __bf16* A, int lda, const __bf16* const (&B)[NB],
                                        int c16, int quad, f32x4 (&acc)[NB][3]) {
#pragma unroll
  for (int i = 0; i < NB; ++i) {
    acc[i][0] = f32x4{0,0,0,0}; acc[i][1] = f32x4{0,0,0,0}; acc[i][2] = f32x4{0,0,0,0};
  }
#pragma unroll
  for (int ks = 0; ks < KS; ++ks) {
    int ko = ks * 32 + quad * 8;
    bf16x8 a0 = ld8(A + c16 * lda + ko);
    bf16x8 a1 = ld8(A + (16 + c16) * lda + ko);
    bf16x8 a2 = ld8(A + (32 + c16) * lda + ko);
#pragma unroll
    for (int i = 0; i < NB; ++i) {
      bf16x8 b = ld8(B[i] + ko);
      acc[i][0] = MFMA(a0, b, acc[i][0]);
      acc[i][1] = MFMA(a1, b, acc[i][1]);
      acc[i][2] = MFMA(a2, b, acc[i][2]);
    }
  }
}

// LayerNorm update; res in C-layout (cols (2w+nt)*16+c16); rewrites res + xbf. 3 barriers.
__device__ __forceinline__ void ln_update(float (&res)[3][2][4], const float* __restrict__ g,
                                          const float* __restrict__ bb, __bf16* xbf, float* part,
                                          float* statsA, float* statsB, int tid, int w, int c16,
                                          int quad) {
#pragma unroll
  for (int mt = 0; mt < 3; ++mt)
#pragma unroll
    for (int r = 0; r < 4; ++r) {
      float s = res[mt][0][r] + res[mt][1][r];
      float ss = res[mt][0][r] * res[mt][0][r] + res[mt][1][r] * res[mt][1][r];
      s += __shfl_xor(s, 1); ss += __shfl_xor(ss, 1);
      s += __shfl_xor(s, 2); ss += __shfl_xor(ss, 2);
      s += __shfl_xor(s, 4); ss += __shfl_xor(ss, 4);
      s += __shfl_xor(s, 8); ss += __shfl_xor(ss, 8);
      if (c16 == 0) {
        int row = mt * 16 + quad * 4 + r;
        part[(w * 48 + row) * 2] = s; part[(w * 48 + row) * 2 + 1] = ss;
      }
    }
  __syncthreads();
  if (tid < 48) {
    float S = 0.f, SS = 0.f;
#pragma unroll
    for (int w2 = 0; w2 < 4; ++w2) { S += part[(w2 * 48 + tid) * 2]; SS += part[(w2 * 48 + tid) * 2 + 1]; }
    float mu = S * 0.0078125f;
    float var = fmaxf(SS * 0.0078125f - mu * mu, 0.f);
    statsA[tid] = mu; statsB[tid] = rsqrtf(var + 1e-5f);
  }
  __syncthreads();
  float gg[2], bv[2];
#pragma unroll
  for (int nt = 0; nt < 2; ++nt) { int col = (2 * w + nt) * 16 + c16; gg[nt] = g[col]; bv[nt] = bb[col]; }
#pragma unroll
  for (int mt = 0; mt < 3; ++mt)
#pragma unroll
    for (int r = 0; r < 4; ++r) {
      int row = mt * 16 + quad * 4 + r;
      float mu = statsA[row], rs = statsB[row];
#pragma unroll
      for (int nt = 0; nt < 2; ++nt) {
        float v = (res[mt][nt][r] - mu) * rs * gg[nt] + bv[nt];
        res[mt][nt][r] = v;
        xbf[row * 136 + (2 * w + nt) * 16 + c16] = (__bf16)(row < NN_ ? v : 0.f);
      }
    }
  __syncthreads();
}

// ---------------- per-tree fused encoder: wave-private attention ----------------
__global__ __launch_bounds__(256, 2) void tree_enc(
    const float* __restrict__ forest, const int* __restrict__ adjacency,
    const int* __restrict__ node_order, const float* __restrict__ b_in,
    const float* __restrict__ qkv_b, const float* __restrict__ ao_b,
    const float* __restrict__ ff1_b, const float* __restrict__ ff2_b,
    const float* __restrict__ ln1_g, const float* __restrict__ ln1_b,
    const float* __restrict__ ln2_g, const float* __restrict__ ln2_b,
    const __bf16* __restrict__ wb, __bf16* __restrict__ Xg) {
  const int f = blockIdx.x, tid = threadIdx.x;
  const int lane = tid & 63, w = tid >> 6, c16 = lane & 15, quad = lane >> 4;

  __shared__ alignas(16) unsigned char smem[SM_SZ];
  __bf16* qk     = (__bf16*)(smem + SM_QK + w * 6912);  // per-wave [48][72]: q cols 0..31, k cols 32..63
  __bf16* fbf    = (__bf16*)(smem + SM_QK);             // [48][40] (init only)
  __bf16* hbf    = (__bf16*)(smem + SM_QK);             // [48][264] (FF only)
  __bf16* xbf    = (__bf16*)(smem + SM_XO);             // [48][136] x / attn-o (aliased)
  __bf16* vt     = (__bf16*)(smem + SM_VT + w * 3584);  // per-wave [32][56] V^T
  __bf16* pos    = (__bf16*)(smem + SM_VT);             // [48][128] (init only; values exactly 0/1)
  float*  part   = (float*)(smem + SM_PART);
  float*  statsA = (float*)(smem + SM_SA);
  float*  statsB = (float*)(smem + SM_SB);
  int*    adj_s  = (int*)(smem + SM_ADJ);
  int*    depth_s= (int*)(smem + SM_DEP);

  // ---- init phase 1: zeros, adjacency, depths ----
  for (int i = tid; i < 960; i += 256) ((int*)fbf)[i] = 0;
  for (int i = tid; i < 3072; i += 256) ((int*)pos)[i] = 0;
  if (tid < E_ * 3) adj_s[tid] = adjacency[f * (E_ * 3) + tid];
  if (w == 1) {
    int v = (lane < NN_) ? node_order[f * NN_ + lane] : 0;
    int mx = v;
#pragma unroll
    for (int m = 1; m < 64; m <<= 1) mx = max(mx, __shfl_xor(mx, m));
    if (lane < 48) depth_s[lane] = (lane < NN_) ? (mx - v) : 0;
  }
  __syncthreads();

  // ---- init phase 2: stage forest bf16 + positional walk (wave 0; parent idx < child idx) ----
  for (int i = tid; i < NN_ * 32; i += 256) {
    int r = i >> 5, c = i & 31;
    fbf[r * 40 + c] = (__bf16)forest[f * (NN_ * 32) + i];
  }
  if (w == 0) {
    for (int e = 0; e < E_; ++e) {
      int p = adj_s[e * 3], c = adj_s[e * 3 + 1], s = adj_s[e * 3 + 2];
      if (p >= 0 && c >= 0) {
        int pl = p - f * NN_, cl = c - f * NN_;
        int si = s + 1; si = si < 0 ? 0 : (si > 2 ? 2 : si);
        int idx = depth_s[pl] * 3 + si;
        float a0 = (lane == idx) ? 1.f : 0.f;
        float a1 = (lane + 64 == idx) ? 1.f : 0.f;
        pos[cl * 128 + lane] = (__bf16)((float)pos[pl * 128 + lane] + a0);
        pos[cl * 128 + 64 + lane] = (__bf16)((float)pos[pl * 128 + 64 + lane] + a1);
      }
    }
  }
  __syncthreads();

  // ---- embed: x0 = forest @ W_in^T + b_in + pos ----
  float res[3][2][4];
  {
    const __bf16* Bw[2] = { wb + WB_WIN + ((2 * w) * 16 + c16) * 32,
                            wb + WB_WIN + ((2 * w + 1) * 16 + c16) * 32 };
    f32x4 ea[2][3];
    gemm3xN<2, 1>(fbf, 40, Bw, c16, quad, ea);
#pragma unroll
    for (int nt = 0; nt < 2; ++nt) {
      float bi = b_in[(2 * w + nt) * 16 + c16];
#pragma unroll
      for (int mt = 0; mt < 3; ++mt)
#pragma unroll
        for (int r = 0; r < 4; ++r) {
          int row = mt * 16 + quad * 4 + r;
          int col = (2 * w + nt) * 16 + c16;
          float v = ea[nt][mt][r] + bi + (float)pos[row * 128 + col];
          res[mt][nt][r] = v;
          xbf[row * 136 + col] = (__bf16)(row < NN_ ? v : 0.f);
        }
    }
  }
  __syncthreads();

  // ---- encoder layers ----
  for (int l = 0; l < 2; ++l) {
    // === per-wave qkv GEMM, head h = w ===
    {
      const __bf16* qkvW = wb + WB_QKV + l * 384 * 128;
      const float* qbl = qkv_b + l * 384;
      f32x4 qa[6][3];
#pragma unroll
      for (int t = 0; t < 6; ++t) { qa[t][0] = f32x4{0,0,0,0}; qa[t][1] = f32x4{0,0,0,0}; qa[t][2] = f32x4{0,0,0,0}; }
      const __bf16* Bp[6];
#pragma unroll
      for (int t = 0; t < 6; ++t) {
        int p = t >> 1, s = t & 1;
        Bp[t] = qkvW + (p * 128 + w * 32 + s * 16 + c16) * 128;
      }
#pragma unroll
      for (int ks = 0; ks < 4; ++ks) {
        int ko = ks * 32 + quad * 8;
        bf16x8 a0 = ld8(xbf + c16 * 136 + ko);
        bf16x8 a1 = ld8(xbf + (16 + c16) * 136 + ko);
        bf16x8 a2 = ld8(xbf + (32 + c16) * 136 + ko);
#pragma unroll
        for (int t = 0; t < 6; ++t) {
          bf16x8 b = ld8(Bp[t] + ko);
          qa[t][0] = MFMA(a0, b, qa[t][0]);
          qa[t][1] = MFMA(a1, b, qa[t][1]);
          qa[t][2] = MFMA(a2, b, qa[t][2]);
        }
      }
#pragma unroll
      for (int t = 0; t < 6; ++t) {
        int p = t >> 1, s = t & 1;
        float bias = qbl[p * 128 + w * 32 + s * 16 + c16];
#pragma unroll
        for (int mt = 0; mt < 3; ++mt) {
          if (p == 2) {  // V -> vt[d][node], nodes contiguous per f32x4 -> b64 store
            bf16x4 pk;
#pragma unroll
            for (int r = 0; r < 4; ++r) pk[r] = (__bf16)(qa[t][mt][r] + bias);
            *(bf16x4*)(vt + (s * 16 + c16) * 56 + mt * 16 + quad * 4) = pk;
          } else {       // Q (scaled) / K -> qk[node][col]
            int colo = (p == 0 ? 0 : 32) + s * 16 + c16;
#pragma unroll
            for (int r = 0; r < 4; ++r) {
              float v = qa[t][mt][r] + bias;
              if (p == 0) v *= SCALE_;
              qk[(mt * 16 + quad * 4 + r) * 72 + colo] = (__bf16)v;
            }
          }
        }
      }
    }
    __syncthreads();  // guards xbf reads (qkv) vs obf writes (PV) across waves

    // === scores S^T = K Q^T, 9 tiles in-register ===
    f32x4 st[3][3];
    {
      bf16x8 ka[3], qb2[3];
#pragma unroll
      for (int m = 0; m < 3; ++m) ka[m] = ld8(qk + (m * 16 + c16) * 72 + 32 + quad * 8);
#pragma unroll
      for (int n = 0; n < 3; ++n) qb2[n] = ld8(qk + (n * 16 + c16) * 72 + quad * 8);
#pragma unroll
      for (int m = 0; m < 3; ++m)
#pragma unroll
        for (int n = 0; n < 3; ++n) {
          f32x4 z{0,0,0,0};
          st[m][n] = MFMA(ka[m], qb2[n], z);
        }
    }

    // === softmax fully in-register (query = n-tile*16 + c16; keys on quad/reg) ===
    int dwp[3][3][2];  // packed P bf16 pairs [key-tile][query-tile][dword]
#pragma unroll
    for (int n = 0; n < 3; ++n) {
      float mx = -3.0e38f;
#pragma unroll
      for (int m = 0; m < 3; ++m)
#pragma unroll
        for (int r = 0; r < 4; ++r) {
          bool valid = (m < 2) || (quad * 4 + r < 10);  // key < 42
          mx = fmaxf(mx, valid ? st[m][n][r] : -3.0e38f);
        }
      mx = fmaxf(mx, __shfl_xor(mx, 16));
      mx = fmaxf(mx, __shfl_xor(mx, 32));
      float sm = 0.f, ev[3][4];
#pragma unroll
      for (int m = 0; m < 3; ++m)
#pragma unroll
        for (int r = 0; r < 4; ++r) {
          bool valid = (m < 2) || (quad * 4 + r < 10);
          float e = valid ? __expf(st[m][n][r] - mx) : 0.f;
          ev[m][r] = e; sm += e;
        }
      sm += __shfl_xor(sm, 16);
      sm += __shfl_xor(sm, 32);
      float inv = 1.f / sm;
#pragma unroll
      for (int m = 0; m < 3; ++m) {
        dwp[m][n][0] = pack2(ev[m][0] * inv, ev[m][1] * inv);
        dwp[m][n][1] = pack2(ev[m][2] * inv, ev[m][3] * inv);
      }
    }

    // === PV via shuffle-transpose of P (no LDS round-trip) ===
    f32x4 ov[3][2];
#pragma unroll
    for (int mtq = 0; mtq < 3; ++mtq) { ov[mtq][0] = f32x4{0,0,0,0}; ov[mtq][1] = f32x4{0,0,0,0}; }
    int sl0 = (2 * (quad & 1)) * 16 + c16, sl1 = sl0 + 16;
    bool hi = quad > 1;
#pragma unroll
    for (int ks = 0; ks < 2; ++ks) {
      int koB = 32 * ks + ((ks == 1 && quad > 1) ? (quad & 1) * 8 : quad * 8);  // clamped; A=0 there
      bf16x8 bv0 = ld8(vt + (0 * 16 + c16) * 56 + koB);
      bf16x8 bv1 = ld8(vt + (1 * 16 + c16) * 56 + koB);
      int lo = 2 * ks;
#pragma unroll
      for (int mtq = 0; mtq < 3; ++mtq) {
        int a0 = __shfl(dwp[lo][mtq][0], sl0), a1 = __shfl(dwp[lo][mtq][1], sl0);
        int a2 = __shfl(dwp[lo][mtq][0], sl1), a3 = __shfl(dwp[lo][mtq][1], sl1);
        int b0 = 0, b1 = 0, b2 = 0, b3 = 0;
        if (ks == 0) {
          b0 = __shfl(dwp[1][mtq][0], sl0); b1 = __shfl(dwp[1][mtq][1], sl0);
          b2 = __shfl(dwp[1][mtq][0], sl1); b3 = __shfl(dwp[1][mtq][1], sl1);
        }
        union { int i[4]; bf16x8 v; } A;
        A.i[0] = hi ? b0 : a0; A.i[1] = hi ? b1 : a1;
        A.i[2] = hi ? b2 : a2; A.i[3] = hi ? b3 : a3;
        ov[mtq][0] = MFMA(A.v, bv0, ov[mtq][0]);
        ov[mtq][1] = MFMA(A.v, bv1, ov[mtq][1]);
      }
    }
    // obf (= xbf alias) write: head slab cols w*32..w*32+31
#pragma unroll
    for (int mtq = 0; mtq < 3; ++mtq)
#pragma unroll
      for (int nt = 0; nt < 2; ++nt)
#pragma unroll
        for (int r = 0; r < 4; ++r) {
          int row = mtq * 16 + quad * 4 + r;
          xbf[row * 136 + w * 32 + nt * 16 + c16] = (__bf16)(row < NN_ ? ov[mtq][nt][r] : 0.f);
        }
    __syncthreads();

    // === attn-out + residual ===
    {
      const __bf16* aoW = wb + WB_AO + l * 128 * 128;
      const __bf16* Bs[2] = { aoW + ((2 * w) * 16 + c16) * 128, aoW + ((2 * w + 1) * 16 + c16) * 128 };
      f32x4 aa[2][3];
      gemm3xN<2, 4>(xbf, 136, Bs, c16, quad, aa);
#pragma unroll
      for (int nt = 0; nt < 2; ++nt) {
        float ab = ao_b[l * 128 + (2 * w + nt) * 16 + c16];
#pragma unroll
        for (int mt = 0; mt < 3; ++mt)
#pragma unroll
          for (int r = 0; r < 4; ++r) res[mt][nt][r] += aa[nt][mt][r] + ab;
      }
    }
    ln_update(res, ln1_g + l * 128, ln1_b + l * 128, xbf, part, statsA, statsB, tid, w, c16, quad);

    // === FF1 -> hbf (relu, bf16) ===
    {
      const __bf16* f1W = wb + WB_FF1 + l * 256 * 128;
      const __bf16* Bs[4] = { f1W + ((4 * w) * 16 + c16) * 128, f1W + ((4 * w + 1) * 16 + c16) * 128,
                              f1W + ((4 * w + 2) * 16 + c16) * 128, f1W + ((4 * w + 3) * 16 + c16) * 128 };
      f32x4 fa[4][3];
      gemm3xN<4, 4>(xbf, 136, Bs, c16, quad, fa);
#pragma unroll
      for (int nt = 0; nt < 4; ++nt) {
        int col = (4 * w + nt) * 16 + c16;
        float b1 = ff1_b[l * 256 + col];
#pragma unroll
        for (int mt = 0; mt < 3; ++mt)
#pragma unroll
          for (int r = 0; r < 4; ++r) {
            int row = mt * 16 + quad * 4 + r;
            float v = fmaxf(fa[nt][mt][r] + b1, 0.f);
            hbf[row * 264 + col] = (__bf16)(row < NN_ ? v : 0.f);
          }
      }
    }
    __syncthreads();

    // === FF2 + residual ===
    {
      const __bf16* f2W = wb + WB_FF2 + l * 128 * 256;
      const __bf16* Bs[2] = { f2W + ((2 * w) * 16 + c16) * 256, f2W + ((2 * w + 1) * 16 + c16) * 256 };
      f32x4 fa[2][3];
      gemm3xN<2, 8>(hbf, 264, Bs, c16, quad, fa);
#pragma unroll
      for (int nt = 0; nt < 2; ++nt) {
        float fb2 = ff2_b[l * 128 + (2 * w + nt) * 16 + c16];
#pragma unroll
        for (int mt = 0; mt < 3; ++mt)
#pragma unroll
          for (int r = 0; r < 4; ++r) res[mt][nt][r] += fa[nt][mt][r] + fb2;
      }
    }
    ln_update(res, ln2_g + l * 128, ln2_b + l * 128, xbf, part, statsA, statsB, tid, w, c16, quad);
  }

  // ---- stage out: x_final (bf16) -> ws X[f][5376] ----
  {
    __bf16* Xf = Xg + (size_t)f * 5376;
    for (int c = tid; c < 672; c += 256) {
      int row = c >> 4, co = (c & 15) * 8;
      *(bf16x8*)(Xf + row * 128 + co) = ld8(xbf + row * 136 + co);
    }
  }
}

// ---------------- output projection + final LN, K split across wave-pairs ----------------
__global__ __launch_bounds__(512) void wout_k(const __bf16* __restrict__ X,
                                              const __bf16* __restrict__ Wb,
                                              const float* __restrict__ b_out,
                                              const float* __restrict__ lnf_g,
                                              const float* __restrict__ lnf_b,
                                              float* __restrict__ out) {
  const int blk = blockIdx.x, tid = threadIdx.x;
  const int lane = tid & 63, w2 = tid >> 6, wc = w2 & 3, kh = w2 >> 2;
  const int c16 = lane & 15, quad = lane >> 4;
  __shared__ float cout[32 * 132];
  f32x4 acc0{0,0,0,0}, acc1{0,0,0,0};
  const __bf16* Ar = X + (size_t)(blk * 16 + c16) * 5376 + kh * 2688;
  const __bf16* B0 = Wb + (size_t)((2 * wc) * 16 + c16) * 5376 + kh * 2688;
  const __bf16* B1 = Wb + (size_t)((2 * wc + 1) * 16 + c16) * 5376 + kh * 2688;
#pragma unroll 4
  for (int ks = 0; ks < 84; ++ks) {
    int ko = ks * 32 + quad * 8;
    bf16x8 a = ld8(Ar + ko);
    acc0 = MFMA(a, ld8(B0 + ko), acc0);
    acc1 = MFMA(a, ld8(B1 + ko), acc1);
  }
#pragma unroll
  for (int nt = 0; nt < 2; ++nt) {
    f32x4 a = nt ? acc1 : acc0;
#pragma unroll
    for (int r = 0; r < 4; ++r) cout[(kh * 16 + quad * 4 + r) * 132 + (2 * wc + nt) * 16 + c16] = a[r];
  }
  __syncthreads();
  if (w2 < 4) {
#pragma unroll
    for (int rr = 0; rr < 4; ++rr) {
      int row = w2 * 4 + rr;
      float v0 = cout[row * 132 + lane] + cout[(16 + row) * 132 + lane] + b_out[lane];
      float v1 = cout[row * 132 + 64 + lane] + cout[(16 + row) * 132 + 64 + lane] + b_out[64 + lane];
      float s = v0 + v1, ss = v0 * v0 + v1 * v1;
#pragma unroll
      for (int m = 1; m < 64; m <<= 1) { s += __shfl_xor(s, m); ss += __shfl_xor(ss, m); }
      float mu = s * 0.0078125f;
      float var = fmaxf(ss * 0.0078125f - mu * mu, 0.f);
      float rs = rsqrtf(var + 1e-5f);
      size_t o = (size_t)(blk * 16 + row) * 128;
      out[o + lane] = (v0 - mu) * rs * lnf_g[lane] + lnf_b[lane];
      out[o + 64 + lane] = (v1 - mu) * rs * lnf_g[64 + lane] + lnf_b[64 + lane];
    }
  }
}

extern "C" void kernel_launch(void* const* d_in, const int* in_sizes, int n_in,
                              void* d_out, int out_size, void* d_ws, size_t ws_size,
                              hipStream_t stream) {
  const float* forest     = (const float*)d_in[0];
  const int*   adjacency  = (const int*)d_in[1];
  const int*   node_order = (const int*)d_in[2];
  const float* W_in       = (const float*)d_in[3];
  const float* b_in       = (const float*)d_in[4];
  const float* qkv_w      = (const float*)d_in[5];
  const float* qkv_b      = (const float*)d_in[6];
  const float* ao_w       = (const float*)d_in[7];
  const float* ao_b       = (const float*)d_in[8];
  const float* ff1_w      = (const float*)d_in[9];
  const float* ff1_b      = (const float*)d_in[10];
  const float* ff2_w      = (const float*)d_in[11];
  const float* ff2_b      = (const float*)d_in[12];
  const float* ln1_g      = (const float*)d_in[13];
  const float* ln1_b      = (const float*)d_in[14];
  const float* ln2_g      = (const float*)d_in[15];
  const float* ln2_b      = (const float*)d_in[16];
  const float* b_out      = (const float*)d_in[18];
  const float* lnf_g      = (const float*)d_in[19];
  const float* lnf_b      = (const float*)d_in[20];
  __bf16* wb = (__bf16*)d_ws;
  float* out = (float*)d_out;

  prep_bf16<<<dim3(PREP_N / 256), dim3(256), 0, stream>>>(W_in, qkv_w, ao_w, ff1_w, ff2_w,
                                                          (const float*)d_in[17], wb);
  tree_enc<<<dim3(FB_), dim3(256), 0, stream>>>(forest, adjacency, node_order, b_in, qkv_b, ao_b,
                                                ff1_b, ff2_b, ln1_g, ln1_b, ln2_g, ln2_b, wb,
                                                wb + WB_X);
  wout_k<<<dim3(FB_ / 16), dim3(512), 0, stream>>>(wb + WB_X, wb + WB_WOUT, b_out, lnf_g, lnf_b,
                                                   out);
}